// Round 3
// baseline (789.081 us; speedup 1.0000x reference)
//
#include <hip/hip_runtime.h>

// MixedScaleDenseLayer: out[n, 0:32]  = x
//                       out[n, 32+j]  = bias[j] + sum_c conv3x3_dilated(x[n,c], W[j,c], d=j+1)
// x: [8,32,512,512] f32, W: [10,32,3,3] f32, b: [10] f32, out: [8,42,512,512] f32
//
// 16x128 output tile per 256-thread block; channels in pairs packed as half2;
// v_dot2_f32_f16 (fdot2) does 2 MACs/instr with f32 accumulate. Thread owns
// 8 consecutive w pixels x 10 dilations (80 f32 accums).
//
// Round-3 change: LDS tile stored as 16B SLOTS (float4 = 4 half2) with an XOR
// slot swizzle q^=(q>>3)&7. All compute-loop LDS reads are ds_read_b128
// (120/thread/cp) instead of 408 ds_read_b32 -- the b32 version saturated the
// LDS pipe (~90% of kernel cycles; b32 moves 44 B/cyc vs b128 85 B/cyc, m134).
// Swizzle makes both the read pattern (4 rows x 16 wi, slot 2wi+sl) and the
// staging write pattern (consecutive slots) hit each 4-bank group exactly 8x
// per instr = the b128 hardware minimum (conflict-free). Involution => writer
// and reader agree. Logical slots 38,39 (cols >=152) are never read, so their
// physical images (34,35) may hold stale data.
//
// Occupancy history: no-attr: 136 VGPR, 3 blk/CU, 595us. launch_bounds(256,4):
// allocator split to 64 VGPR + AGPR spill (hbm +0.58 GB scratch/AGPR traffic),
// 436us. waves_per_eu(4,4): 421us, same split. LDS pipe is the real wall.

#define TH    16
#define TW    128
#define HALO  10
#define PADW  12
#define SH    (TH + 2 * HALO)   // 36 staged rows
#define SLOTS 40                // 16B slots per staged row (640 B row stride)
#define DSLOT 38                // data slots per row (cols 0..151)
#define NCP   16                // channel pairs
#define ND    10                // dilations
#define IMG   512

// __fp16 (not _Float16): matches clang's __builtin_amdgcn_{fdot2,cvt_pkrtz}
// signatures ("V2h" = vector of 2 __fp16).
typedef __fp16 half2v __attribute__((ext_vector_type(2)));

#if defined(__has_builtin)
#  if __has_builtin(__builtin_amdgcn_fdot2)
#    define HAVE_FDOT2 1
#  endif
#endif

__device__ __forceinline__ float dot2f(half2v a, half2v w, float c) {
#ifdef HAVE_FDOT2
  return __builtin_amdgcn_fdot2(a, w, c, false);
#else
  return c + (float)a[0] * (float)w[0] + (float)a[1] * (float)w[1];
#endif
}

__device__ __forceinline__ half2v pack2(float a, float b) {
#if defined(__has_builtin) && __has_builtin(__builtin_amdgcn_cvt_pkrtz)
  return __builtin_amdgcn_cvt_pkrtz(a, b);
#else
  half2v r; r[0] = (__fp16)a; r[1] = (__fp16)b; return r;
#endif
}

// slot swizzle: bijective involution on [0,40)
#define SWZQ(q) ((q) ^ (((q) >> 3) & 7))

__global__ __launch_bounds__(256)
__attribute__((amdgpu_waves_per_eu(4, 4)))
void msd_kernel(const float* __restrict__ x, const float* __restrict__ W,
                const float* __restrict__ b, float* __restrict__ out) {
  __shared__ float4 tile[SH * SLOTS];   // 23040 B
  __shared__ half2v wlds[NCP * 90];     //  5760 B

  const int tid = threadIdx.x;
  const int h0  = blockIdx.x * TH;   // h-tiles fastest: h-halo L2 locality
  const int w0  = blockIdx.y * TW;
  const int n   = blockIdx.z;

  // stage packed per-channel-pair weights: wlds[cp*90 + j*9 + kh*3 + kw]
  for (int s = tid; s < NCP * 90; s += 256) {
    int cp = s / 90;
    int r  = s - cp * 90;          // j*9 + kh*3 + kw
    int j  = r / 9;
    int t9 = r - j * 9;
    float wa = W[(j * 32 + 2 * cp) * 9 + t9];
    float wb = W[(j * 32 + 2 * cp + 1) * 9 + t9];
    wlds[s] = pack2(wa, wb);
  }

  const int row = tid >> 4;          // 0..15 (output row within tile)
  const int wi  = tid & 15;          // 0..15 (8-pixel chunk within tile)
  const int h   = h0 + row;
  const int wb_ = w0 + wi * 8;

  // per-thread swizzled slot offsets (slot units), reused for every row/cp.
  // window slots are 2*wi + sl, sl = 0..7  (covers half2 positions 8wi..8wi+31)
  int co[8];
  #pragma unroll
  for (int sl = 0; sl < 8; ++sl) co[sl] = SWZQ(2 * wi + sl);
  const float4* tb = &tile[row * SLOTS];   // accessed rows: row + 10 +- d (>= row)

  float acc[ND][8];
  #pragma unroll
  for (int d = 0; d < ND; ++d) {
    float bv = b[d];
    #pragma unroll
    for (int j = 0; j < 8; ++j) acc[d][j] = bv;
  }

  for (int cp = 0; cp < NCP; ++cp) {
    __syncthreads();   // previous iter's readers done (also covers wlds, iter 0)
    {
      const float* xa  = x + (((size_t)n * 32 + 2 * cp) * IMG) * IMG;
      const float* xbp = xa + (size_t)IMG * IMG;
      for (int s = tid; s < SH * DSLOT; s += 256) {   // 1368 slots
        int r  = s / DSLOT;
        int q  = s - r * DSLOT;
        int gh = h0 - HALO + r;
        int gw = w0 - PADW + 4 * q;
        float va[4] = {0.f, 0.f, 0.f, 0.f};
        float vb[4] = {0.f, 0.f, 0.f, 0.f};
        if ((unsigned)gh < (unsigned)IMG) {
          const float* pa = xa  + (size_t)gh * IMG;
          const float* pb = xbp + (size_t)gh * IMG;
          if (gw >= 0 && gw + 3 < IMG) {
            float4 t0 = *(const float4*)(pa + gw);
            float4 t1 = *(const float4*)(pb + gw);
            va[0] = t0.x; va[1] = t0.y; va[2] = t0.z; va[3] = t0.w;
            vb[0] = t1.x; vb[1] = t1.y; vb[2] = t1.z; vb[3] = t1.w;
          } else {
            #pragma unroll
            for (int i = 0; i < 4; ++i) {
              int c = gw + i;
              if ((unsigned)c < (unsigned)IMG) { va[i] = pa[c]; vb[i] = pb[c]; }
            }
          }
        }
        float4 wv;
        wv.x = __builtin_bit_cast(float, pack2(va[0], vb[0]));
        wv.y = __builtin_bit_cast(float, pack2(va[1], vb[1]));
        wv.z = __builtin_bit_cast(float, pack2(va[2], vb[2]));
        wv.w = __builtin_bit_cast(float, pack2(va[3], vb[3]));
        tile[r * SLOTS + SWZQ(q)] = wv;
      }
    }
    __syncthreads();

    const half2v* wp = &wlds[cp * 90];

    // ---- center row (kh = 1) + fused x-copy ----
    {
      half2v hk[32];                 // half2 at window pos t; tap t = 12 + j + (kw-1)*d
      #pragma unroll
      for (int sl = 0; sl < 8; ++sl) {
        float4 v = tb[10 * SLOTS + co[sl]];
        hk[4 * sl + 0] = __builtin_bit_cast(half2v, v.x);
        hk[4 * sl + 1] = __builtin_bit_cast(half2v, v.y);
        hk[4 * sl + 2] = __builtin_bit_cast(half2v, v.z);
        hk[4 * sl + 3] = __builtin_bit_cast(half2v, v.w);
      }

      // copy-out: x value at (h, wb_+j) is hk[12+j]
      float* o0 = out + (((size_t)n * 42 + 2 * cp) * IMG + h) * IMG + wb_;
      float* o1 = o0 + (size_t)IMG * IMG;
      *(float4*)o0       = make_float4((float)hk[12][0], (float)hk[13][0], (float)hk[14][0], (float)hk[15][0]);
      *(float4*)(o0 + 4) = make_float4((float)hk[16][0], (float)hk[17][0], (float)hk[18][0], (float)hk[19][0]);
      *(float4*)o1       = make_float4((float)hk[12][1], (float)hk[13][1], (float)hk[14][1], (float)hk[15][1]);
      *(float4*)(o1 + 4) = make_float4((float)hk[16][1], (float)hk[17][1], (float)hk[18][1], (float)hk[19][1]);

      #pragma unroll
      for (int d = 1; d <= ND; ++d) {
        half2v wv0 = wp[(d - 1) * 9 + 3];
        half2v wv1 = wp[(d - 1) * 9 + 4];
        half2v wv2 = wp[(d - 1) * 9 + 5];
        #pragma unroll
        for (int j = 0; j < 8; ++j) {
          float a0 = acc[d - 1][j];
          a0 = dot2f(hk[12 + j - d], wv0, a0);
          a0 = dot2f(hk[12 + j],     wv1, a0);
          a0 = dot2f(hk[12 + j + d], wv2, a0);
          acc[d - 1][j] = a0;
        }
      }
    }

    // ---- side rows: row offset -d -> kh=0, +d -> kh=2 ----
    #pragma unroll
    for (int d = 1; d <= ND; ++d) {
      const int sl0 = (12 - d) >> 2;         // compile-time after unroll
      const int sl1 = (19 + d) >> 2;
      #pragma unroll
      for (int sgn = 0; sgn < 2; ++sgn) {
        const int ro = 10 + (sgn ? d : -d);  // staged row offset from tb (>= 0)
        const int kh = sgn ? 2 : 0;
        half2v hk[32];
        #pragma unroll
        for (int sl = sl0; sl <= sl1; ++sl) {
          float4 v = tb[ro * SLOTS + co[sl]];
          hk[4 * sl + 0] = __builtin_bit_cast(half2v, v.x);
          hk[4 * sl + 1] = __builtin_bit_cast(half2v, v.y);
          hk[4 * sl + 2] = __builtin_bit_cast(half2v, v.z);
          hk[4 * sl + 3] = __builtin_bit_cast(half2v, v.w);
        }
        half2v wv0 = wp[(d - 1) * 9 + kh * 3 + 0];
        half2v wv1 = wp[(d - 1) * 9 + kh * 3 + 1];
        half2v wv2 = wp[(d - 1) * 9 + kh * 3 + 2];
        #pragma unroll
        for (int j = 0; j < 8; ++j) {
          float a0 = acc[d - 1][j];
          a0 = dot2f(hk[12 + j - d], wv0, a0);
          a0 = dot2f(hk[12 + j],     wv1, a0);
          a0 = dot2f(hk[12 + j + d], wv2, a0);
          acc[d - 1][j] = a0;
        }
      }
    }
  }

  // store conv outputs (channels 32..41)
  #pragma unroll
  for (int d = 0; d < ND; ++d) {
    float* op = out + (((size_t)n * 42 + 32 + d) * IMG + h) * IMG + wb_;
    *(float4*)op       = make_float4(acc[d][0], acc[d][1], acc[d][2], acc[d][3]);
    *(float4*)(op + 4) = make_float4(acc[d][4], acc[d][5], acc[d][6], acc[d][7]);
  }
}

extern "C" void kernel_launch(void* const* d_in, const int* in_sizes, int n_in,
                              void* d_out, int out_size, void* d_ws, size_t ws_size,
                              hipStream_t stream) {
  const float* x = (const float*)d_in[0];
  const float* W = (const float*)d_in[1];
  const float* b = (const float*)d_in[2];
  float* out = (float*)d_out;
  (void)in_sizes; (void)n_in; (void)out_size; (void)d_ws; (void)ws_size;
  dim3 grid(IMG / TH, IMG / TW, 8);   // (32, 4, 8)
  dim3 block(256);
  hipLaunchKernelGGL(msd_kernel, grid, block, 0, stream, x, W, b, out);
}